// Round 6
// baseline (293.045 us; speedup 1.0000x reference)
//
#include <hip/hip_runtime.h>
#include <math.h>

#define BDIM 8
#define IMG 224
#define PP 16
#define GG 14
#define NN 196
#define PD 256
#define DD 128
#define DFFV 256
#define CC 1000
#define ROWS (BDIM * NN)  // 1568

#define NEGINF (-INFINITY)

// ======== K1 embed: grid 784, 128 threads, 2 rows/block ========
// h[rho][d] = max_j(patch[rho][j] + eW[d][j]) + pos[n][d]; hm[rho] = rowmax
__global__ void embed_kernel(const float* __restrict__ x, const float* __restrict__ eW,
                             const float* __restrict__ pos,
                             float* __restrict__ h, float* __restrict__ hm) {
  int r0 = blockIdx.x * 2;
  int t = threadIdx.x;  // d
  int b0 = r0 / NN, n0 = r0 % NN;
  int gi0 = n0 / GG, gj0 = n0 % GG;
  int n1 = n0 + 1;
  int gi1 = n1 / GG, gj1 = n1 % GG;
  const float* xb0 = x + (size_t)b0 * IMG * IMG + (size_t)(gi0 * PP) * IMG + gj0 * PP;
  const float* xb1 = x + (size_t)b0 * IMG * IMG + (size_t)(gi1 * PP) * IMG + gj1 * PP;
  const float4* W4 = reinterpret_cast<const float4*>(eW + (size_t)t * PD);
  float a0 = NEGINF, a1 = NEGINF;
  for (int j4 = 0; j4 < PD / 4; j4++) {
    float4 w = W4[j4];
    int j = j4 * 4;
    int pi = j >> 4, pj = j & 15;
    const float* xr0 = xb0 + (size_t)pi * IMG + pj;
    const float* xr1 = xb1 + (size_t)pi * IMG + pj;
    a0 = fmaxf(a0, xr0[0] + w.x); a0 = fmaxf(a0, xr0[1] + w.y);
    a0 = fmaxf(a0, xr0[2] + w.z); a0 = fmaxf(a0, xr0[3] + w.w);
    a1 = fmaxf(a1, xr1[0] + w.x); a1 = fmaxf(a1, xr1[1] + w.y);
    a1 = fmaxf(a1, xr1[2] + w.z); a1 = fmaxf(a1, xr1[3] + w.w);
  }
  float hv0 = a0 + pos[(size_t)n0 * DD + t];
  float hv1 = a1 + pos[(size_t)n1 * DD + t];
  h[(size_t)r0 * DD + t] = hv0;
  h[(size_t)(r0 + 1) * DD + t] = hv1;
  __shared__ float red[2][2];
  int lane = t & 63, wv = t >> 6;
  float m0 = hv0, m1 = hv1;
#pragma unroll
  for (int mask = 32; mask >= 1; mask >>= 1) {
    m0 = fmaxf(m0, __shfl_xor(m0, mask));
    m1 = fmaxf(m1, __shfl_xor(m1, mask));
  }
  if (lane == 0) { red[wv][0] = m0; red[wv][1] = m1; }
  __syncthreads();
  if (t < 2) hm[r0 + t] = fmaxf(red[0][t], red[1][t]);
}

// ======== K2 qkv: grid 784, 384 threads, 2 rows/block ========
__global__ void qkv_kernel(const float* __restrict__ hin, const float* __restrict__ hmin,
                           const float* __restrict__ qW, const float* __restrict__ kW,
                           const float* __restrict__ vW,
                           float* __restrict__ q, float* __restrict__ k,
                           float* __restrict__ v) {
  int r0 = blockIdx.x * 2;
  int t = threadIdx.x;
  int m = t >> 7, i = t & 127;
  const float* W = (m == 0) ? qW : (m == 1 ? kW : vW);
  float* dst = (m == 0) ? q : (m == 1 ? k : v);
  const float4* W4 = reinterpret_cast<const float4*>(W + (size_t)i * DD);
  const float* x0 = hin + (size_t)r0 * DD;
  const float* x1 = x0 + DD;
  float a0 = NEGINF, a1 = NEGINF;
  for (int j4 = 0; j4 < DD / 4; j4++) {
    float4 w = W4[j4];
    int j = j4 * 4;
    a0 = fmaxf(a0, x0[j + 0] + w.x); a0 = fmaxf(a0, x0[j + 1] + w.y);
    a0 = fmaxf(a0, x0[j + 2] + w.z); a0 = fmaxf(a0, x0[j + 3] + w.w);
    a1 = fmaxf(a1, x1[j + 0] + w.x); a1 = fmaxf(a1, x1[j + 1] + w.y);
    a1 = fmaxf(a1, x1[j + 2] + w.z); a1 = fmaxf(a1, x1[j + 3] + w.w);
  }
  float mx0 = hmin[r0], mx1 = hmin[r0 + 1];
  dst[(size_t)r0 * DD + i] = a0 - mx0;
  dst[(size_t)(r0 + 1) * DD + i] = a1 - mx1;
}

// ======== K3 scores: grid 784 (2 q-rows), 256 threads (196 active) ========
// s[rho][j] = max_d(q[rho][d] + k[b][j][d]); no normalization (canceled by pnorm)
__global__ void scores_kernel(const float* __restrict__ q, const float* __restrict__ k,
                              float* __restrict__ s) {
  int r0 = blockIdx.x * 2;
  int b = r0 / NN;
  int t = threadIdx.x;
  if (t >= NN) return;
  const float4* k4 = reinterpret_cast<const float4*>(k + ((size_t)b * NN + t) * DD);
  const float* q0 = q + (size_t)r0 * DD;
  const float* q1 = q0 + DD;
  float a0 = NEGINF, a1 = NEGINF;
  for (int d4 = 0; d4 < DD / 4; d4++) {
    float4 kv = k4[d4];
    int d = d4 * 4;
    a0 = fmaxf(a0, q0[d + 0] + kv.x); a0 = fmaxf(a0, q0[d + 1] + kv.y);
    a0 = fmaxf(a0, q0[d + 2] + kv.z); a0 = fmaxf(a0, q0[d + 3] + kv.w);
    a1 = fmaxf(a1, q1[d + 0] + kv.x); a1 = fmaxf(a1, q1[d + 1] + kv.y);
    a1 = fmaxf(a1, q1[d + 2] + kv.z); a1 = fmaxf(a1, q1[d + 3] + kv.w);
  }
  s[(size_t)r0 * NN + t] = a0;
  s[(size_t)(r0 + 1) * NN + t] = a1;
}

// ======== K4 PV + pnorm + residual: grid 784, 256 threads, 2 rows/block ========
// a[rho][d] = max_j(s[rho][j] + v[b][j][d]); hout = max(hin, a - rowmax(a)); mout = rowmax(hout)
__global__ void pv_kernel(const float* __restrict__ s, const float* __restrict__ v,
                          const float* __restrict__ hin,
                          float* __restrict__ hout, float* __restrict__ mout) {
  int r0 = blockIdx.x * 2;
  int b = r0 / NN;
  int t = threadIdx.x;
  int d = t & 127, jh = t >> 7;
  const float* s0 = s + (size_t)r0 * NN;
  const float* s1 = s0 + NN;
  const float* vb = v + (size_t)b * NN * DD;
  float a0 = NEGINF, a1 = NEGINF;
  for (int j = jh * 98; j < jh * 98 + 98; j++) {
    float vv = vb[(size_t)j * DD + d];
    a0 = fmaxf(a0, s0[j] + vv);
    a1 = fmaxf(a1, s1[j] + vv);
  }
  __shared__ float comb[2][2][DD];
  __shared__ float red[2][2];
  comb[jh][0][d] = a0;
  comb[jh][1][d] = a1;
  __syncthreads();
  float f0 = 0.f, f1 = 0.f;
  int lane = t & 63, wv = t >> 6;
  if (t < DD) {
    f0 = fmaxf(comb[0][0][t], comb[1][0][t]);
    f1 = fmaxf(comb[0][1][t], comb[1][1][t]);
    float m0 = f0, m1 = f1;
#pragma unroll
    for (int mask = 32; mask >= 1; mask >>= 1) {
      m0 = fmaxf(m0, __shfl_xor(m0, mask));
      m1 = fmaxf(m1, __shfl_xor(m1, mask));
    }
    if (lane == 0) { red[wv][0] = m0; red[wv][1] = m1; }
  }
  __syncthreads();
  if (t < DD) {
    float am0 = fmaxf(red[0][0], red[1][0]);
    float am1 = fmaxf(red[0][1], red[1][1]);
    float hv0 = fmaxf(hin[(size_t)r0 * DD + t], f0 - am0);
    float hv1 = fmaxf(hin[(size_t)(r0 + 1) * DD + t], f1 - am1);
    hout[(size_t)r0 * DD + t] = hv0;
    hout[(size_t)(r0 + 1) * DD + t] = hv1;
    float m0 = hv0, m1 = hv1;
#pragma unroll
    for (int mask = 32; mask >= 1; mask >>= 1) {
      m0 = fmaxf(m0, __shfl_xor(m0, mask));
      m1 = fmaxf(m1, __shfl_xor(m1, mask));
    }
    if (lane == 0) { red[wv][0] = m0; red[wv][1] = m1; }
  }
  __syncthreads();
  if (t < 2) mout[r0 + t] = fmaxf(red[0][t], red[1][t]);
}

// ======== K5 ffn1: grid 784, 256 threads (cols), 2 rows/block ========
// g[rho][i] = max(max_j(h[rho][j] + f1W[i][j]) - hm[rho], tau)
__global__ void ffn1_kernel(const float* __restrict__ hin, const float* __restrict__ hmin,
                            const float* __restrict__ f1W, const float* __restrict__ tau,
                            float* __restrict__ g) {
  int r0 = blockIdx.x * 2;
  int t = threadIdx.x;  // col i in [0,256)
  const float4* W4 = reinterpret_cast<const float4*>(f1W + (size_t)t * DD);
  const float* x0 = hin + (size_t)r0 * DD;
  const float* x1 = x0 + DD;
  float a0 = NEGINF, a1 = NEGINF;
  for (int j4 = 0; j4 < DD / 4; j4++) {
    float4 w = W4[j4];
    int j = j4 * 4;
    a0 = fmaxf(a0, x0[j + 0] + w.x); a0 = fmaxf(a0, x0[j + 1] + w.y);
    a0 = fmaxf(a0, x0[j + 2] + w.z); a0 = fmaxf(a0, x0[j + 3] + w.w);
    a1 = fmaxf(a1, x1[j + 0] + w.x); a1 = fmaxf(a1, x1[j + 1] + w.y);
    a1 = fmaxf(a1, x1[j + 2] + w.z); a1 = fmaxf(a1, x1[j + 3] + w.w);
  }
  float tv = tau[0];
  float mx0 = hmin[r0], mx1 = hmin[r0 + 1];
  g[(size_t)r0 * DFFV + t] = fmaxf(a0 - mx0, tv);
  g[(size_t)(r0 + 1) * DFFV + t] = fmaxf(a1 - mx1, tv);
}

// ======== K6 ffn2 + pnorm + residual: grid 784, 256 threads, 2 rows/block ========
// ff[rho][i] = max_j(g[rho][j] + f2W[i][j]); hout = max(hin, ff - rowmax(ff)); mout = rowmax(hout)
__global__ void ffn2_kernel(const float* __restrict__ g, const float* __restrict__ f2W,
                            const float* __restrict__ hin,
                            float* __restrict__ hout, float* __restrict__ mout) {
  int r0 = blockIdx.x * 2;
  int t = threadIdx.x;
  int i = t & 127, kh = t >> 7;
  const float4* W4 = reinterpret_cast<const float4*>(f2W + (size_t)i * DFFV) + kh * 32;
  const float* x0 = g + (size_t)r0 * DFFV + kh * 128;
  const float* x1 = x0 + DFFV;
  float a0 = NEGINF, a1 = NEGINF;
  for (int j4 = 0; j4 < 32; j4++) {
    float4 w = W4[j4];
    int j = j4 * 4;
    a0 = fmaxf(a0, x0[j + 0] + w.x); a0 = fmaxf(a0, x0[j + 1] + w.y);
    a0 = fmaxf(a0, x0[j + 2] + w.z); a0 = fmaxf(a0, x0[j + 3] + w.w);
    a1 = fmaxf(a1, x1[j + 0] + w.x); a1 = fmaxf(a1, x1[j + 1] + w.y);
    a1 = fmaxf(a1, x1[j + 2] + w.z); a1 = fmaxf(a1, x1[j + 3] + w.w);
  }
  __shared__ float comb[2][2][DD];
  __shared__ float red[2][2];
  comb[kh][0][i] = a0;
  comb[kh][1][i] = a1;
  __syncthreads();
  float f0 = 0.f, f1 = 0.f;
  int lane = t & 63, wv = t >> 6;
  if (t < DD) {
    f0 = fmaxf(comb[0][0][t], comb[1][0][t]);
    f1 = fmaxf(comb[0][1][t], comb[1][1][t]);
    float m0 = f0, m1 = f1;
#pragma unroll
    for (int mask = 32; mask >= 1; mask >>= 1) {
      m0 = fmaxf(m0, __shfl_xor(m0, mask));
      m1 = fmaxf(m1, __shfl_xor(m1, mask));
    }
    if (lane == 0) { red[wv][0] = m0; red[wv][1] = m1; }
  }
  __syncthreads();
  if (t < DD) {
    float fm0 = fmaxf(red[0][0], red[1][0]);
    float fm1 = fmaxf(red[0][1], red[1][1]);
    float hv0 = fmaxf(hin[(size_t)r0 * DD + t], f0 - fm0);
    float hv1 = fmaxf(hin[(size_t)(r0 + 1) * DD + t], f1 - fm1);
    hout[(size_t)r0 * DD + t] = hv0;
    hout[(size_t)(r0 + 1) * DD + t] = hv1;
    float m0 = hv0, m1 = hv1;
#pragma unroll
    for (int mask = 32; mask >= 1; mask >>= 1) {
      m0 = fmaxf(m0, __shfl_xor(m0, mask));
      m1 = fmaxf(m1, __shfl_xor(m1, mask));
    }
    if (lane == 0) { red[wv][0] = m0; red[wv][1] = m1; }
  }
  __syncthreads();
  if (t < 2) mout[r0 + t] = fmaxf(red[0][t], red[1][t]);
}

// ======== K7 head: grid (32, B), 256 threads ========
__global__ void head_kernel(const float* __restrict__ h, const float* __restrict__ hW,
                            const float* __restrict__ lscale, float* __restrict__ out) {
  int cc = blockIdx.x, b = blockIdx.y;
  __shared__ float plds[8][DD];
  __shared__ float pooled[DD];
  __shared__ float gred[8][32];
  int t = threadIdx.x;
  {
    int d4 = t & 31, ng = t >> 5;
    float4 pm = {NEGINF, NEGINF, NEGINF, NEGINF};
    for (int n = ng; n < NN; n += 8) {
      float4 hv = *reinterpret_cast<const float4*>(h + ((size_t)b * NN + n) * DD + d4 * 4);
      pm.x = fmaxf(pm.x, hv.x); pm.y = fmaxf(pm.y, hv.y);
      pm.z = fmaxf(pm.z, hv.z); pm.w = fmaxf(pm.w, hv.w);
    }
    *reinterpret_cast<float4*>(&plds[ng][d4 * 4]) = pm;
  }
  __syncthreads();
  if (t < DD) {
    float m = plds[0][t];
#pragma unroll
    for (int gg = 1; gg < 8; gg++) m = fmaxf(m, plds[gg][t]);
    pooled[t] = m;
  }
  __syncthreads();
  int cl = t & 31, ds = t >> 5;
  int c = cc * 32 + cl;
  float acc = NEGINF;
  if (c < CC) {
    const float4* W4 = reinterpret_cast<const float4*>(hW + (size_t)c * DD) + ds * 4;
#pragma unroll
    for (int kk = 0; kk < 4; kk++) {
      float4 w = W4[kk];
      int db = ds * 16 + kk * 4;
      acc = fmaxf(acc, pooled[db + 0] + w.x);
      acc = fmaxf(acc, pooled[db + 1] + w.y);
      acc = fmaxf(acc, pooled[db + 2] + w.z);
      acc = fmaxf(acc, pooled[db + 3] + w.w);
    }
  }
  gred[ds][cl] = acc;
  __syncthreads();
  if (t < 32) {
    int c2 = cc * 32 + t;
    if (c2 < CC) {
      float m = gred[0][t];
#pragma unroll
      for (int gg = 1; gg < 8; gg++) m = fmaxf(m, gred[gg][t]);
      out[(size_t)b * CC + c2] = m * lscale[0];
    }
  }
}

extern "C" void kernel_launch(void* const* d_in, const int* in_sizes, int n_in,
                              void* d_out, int out_size, void* d_ws, size_t ws_size,
                              hipStream_t stream) {
  const float* x = (const float*)d_in[0];
  const float* embed_W = (const float*)d_in[1];
  const float* pos = (const float*)d_in[2];
  const float* qW[2] = {(const float*)d_in[3], (const float*)d_in[9]};
  const float* kW[2] = {(const float*)d_in[4], (const float*)d_in[10]};
  const float* vW[2] = {(const float*)d_in[5], (const float*)d_in[11]};
  const float* f1W[2] = {(const float*)d_in[6], (const float*)d_in[12]};
  const float* f2W[2] = {(const float*)d_in[7], (const float*)d_in[13]};
  const float* tau[2] = {(const float*)d_in[8], (const float*)d_in[14]};
  const float* headW = (const float*)d_in[15];
  const float* lscale = (const float*)d_in[16];
  float* out = (float*)d_out;

  float* ws = (float*)d_ws;
  size_t o = 0;
  float* h[5]; float* hm[5];
  for (int i = 0; i < 5; i++) { h[i] = ws + o; o += (size_t)ROWS * DD; }
  for (int i = 0; i < 5; i++) { hm[i] = ws + o; o += (size_t)ROWS; }
  float* qb = ws + o; o += (size_t)ROWS * DD;
  float* kb = ws + o; o += (size_t)ROWS * DD;
  float* vb = ws + o; o += (size_t)ROWS * DD;
  float* sb = ws + o; o += (size_t)ROWS * NN;
  float* gb = ws + o; o += (size_t)ROWS * DFFV;

  int nb = ROWS / 2;  // 784

  embed_kernel<<<nb, 128, 0, stream>>>(x, embed_W, pos, h[0], hm[0]);
  for (int l = 0; l < 2; l++) {
    int hi = l * 2;  // input state index: 0 or 2
    qkv_kernel<<<nb, 384, 0, stream>>>(h[hi], hm[hi], qW[l], kW[l], vW[l], qb, kb, vb);
    scores_kernel<<<nb, 256, 0, stream>>>(qb, kb, sb);
    pv_kernel<<<nb, 256, 0, stream>>>(sb, vb, h[hi], h[hi + 1], hm[hi + 1]);
    ffn1_kernel<<<nb, 256, 0, stream>>>(h[hi + 1], hm[hi + 1], f1W[l], tau[l], gb);
    ffn2_kernel<<<nb, 256, 0, stream>>>(gb, f2W[l], h[hi + 1], h[hi + 2], hm[hi + 2]);
  }
  head_kernel<<<dim3(32, BDIM), 256, 0, stream>>>(h[4], headW, lscale, out);
}